// Round 11
// baseline (61.317 us; speedup 1.0000x reference)
//
#include <hip/hip_runtime.h>
#include <stdint.h>

#define CIN   128
#define COUT  256
#define HW    56
#define SP    3136      // 56*56
#define NIMG  32
#define NPIX  (NIMG*SP) // 100352
#define KTOT  (CIN*9)   // 1152

typedef unsigned char u8;
using i32x4 = __attribute__((ext_vector_type(4))) int;

__device__ __forceinline__ u8 sgn_i8(float v) {
  return v > 0.f ? (u8)1 : (v < 0.f ? (u8)0xFF : (u8)0);
}

__device__ __forceinline__ void gl_lds16(const void* g, void* l) {
  __builtin_amdgcn_global_load_lds(
      (const __attribute__((address_space(1))) void*)g,
      (__attribute__((address_space(3))) void*)l, 16, 0, 0);
}

// ---- merged prepass: blocks 0..1151 binarize+K-transpose weights,
// ----                 blocks 1152..4287 binarize + NCHW->NHWC transpose x ----
__global__ void prep(const float* __restrict__ x, const float* __restrict__ w,
                     u8* __restrict__ wT, u8* __restrict__ xt,
                     u8* __restrict__ zerob) {
  const int bid = blockIdx.x;
  const int t = threadIdx.x;
  if (bid < 1152) {
    if (bid == 0 && t < 64) ((uint32_t*)zerob)[t] = 0;
    const int idx = bid * 256 + t;
    const int o = idx / KTOT;
    const int r = idx - o * KTOT;
    const int q = r >> 7;
    const int c = r & 127;
    wT[idx] = sgn_i8(w[(size_t)(o * CIN + c) * 9 + q]);
    return;
  }
  __shared__ u8 tile[128][36];
  const int b = bid - 1152;
  const int n = b / 98;
  const int s0 = (b - n * 98) * 32;
  const int tx = t & 31, ty = t >> 5;
  const float* xb = x + (size_t)n * CIN * SP;
#pragma unroll
  for (int i = 0; i < 16; ++i) {
    int c = ty + (i << 3);
    tile[c][tx] = sgn_i8(xb[(size_t)c * SP + s0 + tx]);
  }
  __syncthreads();
  const int s = t >> 3, cg = t & 7;
  const int c0 = cg << 4;
  uint32_t pk[4];
#pragma unroll
  for (int jj = 0; jj < 4; ++jj) {
    uint32_t a0 = tile[c0 + jj * 4 + 0][s];
    uint32_t a1 = tile[c0 + jj * 4 + 1][s];
    uint32_t a2 = tile[c0 + jj * 4 + 2][s];
    uint32_t a3 = tile[c0 + jj * 4 + 3][s];
    pk[jj] = a0 | (a1 << 8) | (a2 << 16) | (a3 << 24);
  }
  u8* dst = xt + (size_t)(n * SP + s0 + s) * CIN + c0;
  uint4 u; u.x = pk[0]; u.y = pk[1]; u.z = pk[2]; u.w = pk[3];
  *(uint4*)dst = u;
}

// ---- main: r5/r10 inner loop, but ONE block handles BOTH Cout halves ----
// grid 448 (one per nt): halo staged once, then 18 tap-steps (9 per mt);
// epilogue for mt=0 runs mid-kernel so its writes overlap mt=1's compute.
// B: zero-padded halo [6 vh][58 col][128 cin] from packed xt (gl_lds).
// A: per-tap global_load_lds, double-buffered across all 18 taps.
// 512 thr = 8 waves (4M x 2N), per-wave 32x112, acc[2][7].
// LDS = 48KB halo + 2x16KB A = 80KB -> 2 blocks/CU (16 waves/CU).
__global__ __launch_bounds__(512) void conv_mfma(
    const u8* __restrict__ wT, const u8* __restrict__ xt,
    const float* __restrict__ bias, const u8* __restrict__ zerob,
    float* __restrict__ out) {
  __shared__ u8 halo[49152];    // 384 slots x 128 B (348 real)
  __shared__ u8 As[2][16384];   // [128 Cout][128 cin] per tap, swizzled chunks

  // XCD-chunked swizzle (448 = 8*56, bijective)
  const int bid0 = blockIdx.x;
  const int nt2  = (bid0 & 7) * 56 + (bid0 >> 3);   // 0..447
  const int n    = nt2 / 14;      // image
  const int hblk = nt2 - n * 14;  // 4-row block
  const int h0   = hblk * 4;
  const int sp0  = hblk * 224;

  const int t  = threadIdx.x;
  const int wv = t >> 6;          // 0..7
  const int ln = t & 63;

  // staging lane geometry
  const int tRow = t >> 3;                  // 0..63
  const int chs  = (t & 7) ^ (tRow & 7);    // pre-swizzled source chunk

  // ---- prologue: stage halo (6 calls x 64 slots) from packed xt ----
#pragma unroll
  for (int c = 0; c < 6; ++c) {
    const int slot = c * 64 + tRow;
    const int vh  = slot / 58;
    const int col = slot - vh * 58;
    const int gh  = h0 - 1 + vh;
    const bool valid = (slot < 348) && ((unsigned)gh < HW) && (col >= 1) && (col <= 56);
    const u8* src = valid
        ? xt + (((size_t)(n * SP + gh * HW + col - 1)) << 7) + (chs << 4)
        : zerob;
    gl_lds16(src, &halo[c * 8192 + wv * 1024]);
  }

  // ---- A staging: tap 0..17 -> (mt = tap/9, q = tap%9) ----
  const u8* wTbase0 = wT + (size_t)tRow * KTOT + (chs << 4);
  auto stageA = [&](int b, int tap) {
    const int mtq = tap < 9 ? 0 : 1;
    const int q   = tap < 9 ? tap : tap - 9;
    const u8* base = wTbase0 + (size_t)(mtq * 128) * KTOT + q * CIN;
#pragma unroll
    for (int c = 0; c < 2; ++c)
      gl_lds16(base + (size_t)c * 64 * KTOT, &As[b][c * 8192 + wv * 1024]);
  };
  stageA(0, 0);

  // ---- fragment geometry (4M x 2N wave grid, per-wave 32x112) ----
  const int wm = wv >> 1, wn = wv & 1;
  const int lr = ln & 15, kg = ln >> 4;
  const int kgs0 = kg << 4;
  const int rdA0 = ((wm * 32 + lr) << 7) + ((kg ^ (lr & 7)) << 4);
  const int rdA1 = rdA0 + (16 << 7);

  int slotj[7];
#pragma unroll
  for (int j = 0; j < 7; ++j) {
    const int px = wn * 112 + j * 16 + lr;
    const int ph = px / 56;
    slotj[j] = (1 + ph) * 58 + (px - ph * 56) + 1;
  }

  i32x4 acc[2][7];
#pragma unroll
  for (int i = 0; i < 2; ++i)
#pragma unroll
    for (int j = 0; j < 7; ++j) acc[i][j] = (i32x4){0, 0, 0, 0};

  constexpr int DC[9] = {-59, -58, -57, -1, 0, 1, 57, 58, 59};

  // epilogue writer (called per mt half)
  auto epilogue = [&](int mt) {
    const int mrow = mt * 128 + wm * 32 + kg * 4;
    float* obase = out + (size_t)n * COUT * SP + sp0 + wn * 112 + lr;
#pragma unroll
    for (int i = 0; i < 2; ++i) {
#pragma unroll
      for (int r = 0; r < 4; ++r) {
        const int m = mrow + i * 16 + r;
        const float bv = bias[m];
        const float sb = bv > 0.f ? 1.f : (bv < 0.f ? -1.f : 0.f);
        float* op = obase + (size_t)m * SP;
#pragma unroll
        for (int j = 0; j < 7; ++j)
          op[j * 16] = (float)acc[i][j][r] + sb;
      }
    }
  };

#pragma unroll
  for (int tap = 0; tap < 18; ++tap) {
    const int q = tap < 9 ? tap : tap - 9;
    __syncthreads();                 // halo + As[tap&1] ready
    if (tap < 17) stageA((tap + 1) & 1, tap + 1);
    const int buf = tap & 1;
    int ba[7];
#pragma unroll
    for (int j = 0; j < 7; ++j) {
      const int s_t = slotj[j] + DC[q];
      ba[j] = (s_t << 7) + (kgs0 ^ ((s_t & 7) << 4));
    }
    __builtin_amdgcn_s_setprio(1);
#pragma unroll
    for (int kc = 0; kc < 2; ++kc) {
      const i32x4 af0 = *(const i32x4*)&As[buf][rdA0 ^ (kc << 6)];
      const i32x4 af1 = *(const i32x4*)&As[buf][rdA1 ^ (kc << 6)];
#pragma unroll
      for (int j = 0; j < 7; ++j) {
        const i32x4 bf = *(const i32x4*)&halo[ba[j] ^ (kc << 6)];
        acc[0][j] = __builtin_amdgcn_mfma_i32_16x16x64_i8(af0, bf, acc[0][j], 0, 0, 0);
        acc[1][j] = __builtin_amdgcn_mfma_i32_16x16x64_i8(af1, bf, acc[1][j], 0, 0, 0);
      }
    }
    __builtin_amdgcn_s_setprio(0);
    if (tap == 8) {
      epilogue(0);                   // mt=0 writes overlap mt=1 compute
#pragma unroll
      for (int i = 0; i < 2; ++i)
#pragma unroll
        for (int j = 0; j < 7; ++j) acc[i][j] = (i32x4){0, 0, 0, 0};
    }
  }
  epilogue(1);
}

// ---- fallback if workspace is too small: direct conv (slow but correct) ----
__global__ void conv_naive(const float* __restrict__ x, const float* __restrict__ w,
                           const float* __restrict__ bias, float* __restrict__ out) {
  int idx = blockIdx.x * 256 + threadIdx.x;
  const int total = NIMG * COUT * SP;
  if (idx >= total) return;
  int sp = idx % SP;
  int o  = (idx / SP) % COUT;
  int nn = idx / (SP * COUT);
  int h = sp / HW, wx = sp - (sp / HW) * HW;
  float acc = 0.f;
  for (int c = 0; c < CIN; ++c) {
    const float* xp = x + (size_t)(nn * CIN + c) * SP;
    const float* wp = w + (size_t)(o * CIN + c) * 9;
    for (int kh = 0; kh < 3; ++kh) {
      int hhh = h + kh - 1;
      if ((unsigned)hhh >= HW) continue;
      for (int kw = 0; kw < 3; ++kw) {
        int www = wx + kw - 1;
        if ((unsigned)www >= HW) continue;
        float xv = xp[hhh * HW + www];
        float wv = wp[kh * 3 + kw];
        float xs = xv > 0.f ? 1.f : (xv < 0.f ? -1.f : 0.f);
        float wsn = wv > 0.f ? 1.f : (wv < 0.f ? -1.f : 0.f);
        acc += xs * wsn;
      }
    }
  }
  float bv = bias[o];
  out[idx] = acc + (bv > 0.f ? 1.f : (bv < 0.f ? -1.f : 0.f));
}

extern "C" void kernel_launch(void* const* d_in, const int* in_sizes, int n_in,
                              void* d_out, int out_size, void* d_ws, size_t ws_size,
                              hipStream_t stream) {
  const float* x    = (const float*)d_in[0];
  const float* w    = (const float*)d_in[1];
  const float* bias = (const float*)d_in[2];
  float* out = (float*)d_out;

  const size_t need = (size_t)1048576 + (size_t)NPIX * CIN;  // ~13.9 MB
  if (ws_size >= need) {
    u8* zerob = (u8*)d_ws;                        // 256 B zeros
    u8* wT8   = (u8*)((char*)d_ws + 512);         // 256x1152 i8
    u8* xt8   = (u8*)((char*)d_ws + 1048576);     // NHWC i8
    prep<<<1152 + 3136, 256, 0, stream>>>(x, w, wT8, xt8, zerob);
    conv_mfma<<<448, 512, 0, stream>>>(wT8, xt8, bias, zerob, out);
  } else {
    const int total = NIMG * COUT * SP;
    conv_naive<<<(total + 255) / 256, 256, 0, stream>>>(x, w, bias, out);
  }
}

// Round 12
// 48.586 us; speedup vs baseline: 1.2620x; 1.2620x over previous
//
#include <hip/hip_runtime.h>
#include <stdint.h>

#define CIN   128
#define COUT  256
#define HW    56
#define SP    3136      // 56*56
#define NIMG  32
#define NPIX  (NIMG*SP) // 100352
#define KTOT  (CIN*9)   // 1152

typedef unsigned char u8;
using i32x4 = __attribute__((ext_vector_type(4))) int;

__device__ __forceinline__ u8 sgn_i8(float v) {
  return v > 0.f ? (u8)1 : (v < 0.f ? (u8)0xFF : (u8)0);
}

__device__ __forceinline__ void gl_lds16(const void* g, void* l) {
  __builtin_amdgcn_global_load_lds(
      (const __attribute__((address_space(1))) void*)g,
      (__attribute__((address_space(3))) void*)l, 16, 0, 0);
}

// ---- merged prepass: blocks 0..1151 weights, 1152..4287 x transpose ----
__global__ void prep(const float* __restrict__ x, const float* __restrict__ w,
                     u8* __restrict__ wT, u8* __restrict__ xt,
                     u8* __restrict__ zerob) {
  const int bid = blockIdx.x;
  const int t = threadIdx.x;
  if (bid < 1152) {
    if (bid == 0 && t < 64) ((uint32_t*)zerob)[t] = 0;
    const int idx = bid * 256 + t;
    const int o = idx / KTOT;
    const int r = idx - o * KTOT;
    const int q = r >> 7;
    const int c = r & 127;
    wT[idx] = sgn_i8(w[(size_t)(o * CIN + c) * 9 + q]);
    return;
  }
  __shared__ u8 tile[128][36];
  const int b = bid - 1152;
  const int n = b / 98;
  const int s0 = (b - n * 98) * 32;
  const int tx = t & 31, ty = t >> 5;
  const float* xb = x + (size_t)n * CIN * SP;
#pragma unroll
  for (int i = 0; i < 16; ++i) {
    int c = ty + (i << 3);
    tile[c][tx] = sgn_i8(xb[(size_t)c * SP + s0 + tx]);
  }
  __syncthreads();
  const int s = t >> 3, cg = t & 7;
  const int c0 = cg << 4;
  uint32_t pk[4];
#pragma unroll
  for (int jj = 0; jj < 4; ++jj) {
    uint32_t a0 = tile[c0 + jj * 4 + 0][s];
    uint32_t a1 = tile[c0 + jj * 4 + 1][s];
    uint32_t a2 = tile[c0 + jj * 4 + 2][s];
    uint32_t a3 = tile[c0 + jj * 4 + 3][s];
    pk[jj] = a0 | (a1 << 8) | (a2 << 16) | (a3 << 24);
  }
  u8* dst = xt + (size_t)(n * SP + s0 + s) * CIN + c0;
  uint4 u; u.x = pk[0]; u.y = pk[1]; u.z = pk[2]; u.w = pk[3];
  *(uint4*)dst = u;
}

// ---- main: barrier-free K-loop; per-wave private A staging ----
// tile: 128 Cout x 224 px (4 h-rows, image-aligned). B: zero-padded halo
// [6 vh][58 col][128 cin] from packed xt, staged once (only __syncthreads).
// A: each wave stages ITS 32 Cout rows (4 KB) per tap into a private LDS
// region via 4 gl_lds from L2-resident wT; per-tap sync = per-wave
// vmcnt(0) + lgkmcnt(0) (in-place restage), no block barrier -> waves drift
// and overlap LDS/MFMA pipes (m114).
// 512 thr = 8 waves (4M x 2N), per-wave 32x112, acc[2][7].
// LDS = 44544 halo + 8*4096 A = 77312 -> 2 blocks/CU (16 waves/CU).
__global__ __launch_bounds__(512, 4) void conv_mfma(
    const u8* __restrict__ wT, const u8* __restrict__ xt,
    const float* __restrict__ bias, const u8* __restrict__ zerob,
    float* __restrict__ out) {
  __shared__ u8 halo[44544];    // 348 slots x 128 B (reads span slots 0..347)
  __shared__ u8 Aw[8][4096];    // per-wave A tile: 32 rows x 128 B

  // XCD-chunked swizzle (896 = 8*112, bijective); mt pairs stay adjacent.
  const int bid0 = blockIdx.x;
  const int bid  = (bid0 & 7) * 112 + (bid0 >> 3);
  const int mt  = bid & 1;
  const int nt2 = bid >> 1;
  const int n    = nt2 / 14;
  const int hblk = nt2 - n * 14;
  const int h0   = hblk * 4;
  const int sp0  = hblk * 224;

  const int t  = threadIdx.x;
  const int wv = t >> 6;          // 0..7
  const int ln = t & 63;

  // ---- halo staging (6 calls x 64 slots; guard keeps dest within 348) ----
  const int tRow = t >> 3;                  // 0..63
  const int chs  = (t & 7) ^ (tRow & 7);
#pragma unroll
  for (int c = 0; c < 6; ++c) {
    const int slot = c * 64 + tRow;
    if (slot < 348) {
      const int vh  = slot / 58;
      const int col = slot - vh * 58;
      const int gh  = h0 - 1 + vh;
      const bool valid = ((unsigned)gh < HW) && (col >= 1) && (col <= 56);
      const u8* src = valid
          ? xt + (((size_t)(n * SP + gh * HW + col - 1)) << 7) + (chs << 4)
          : zerob;
      gl_lds16(src, &halo[c * 8192 + wv * 1024]);
    }
  }

  // ---- per-wave A staging geometry ----
  const int wm = wv >> 1, wn = wv & 1;
  const int lrow = ln >> 3;                 // local row within 8-row call
  const int Achs = (ln & 7) ^ lrow;         // pre-swizzled source chunk
  const u8* awbase = wT + (size_t)((mt << 7) + (wm << 5) + lrow) * KTOT + (Achs << 4);
  auto stageA = [&](int q) {
#pragma unroll
    for (int c = 0; c < 4; ++c)
      gl_lds16(awbase + (size_t)(c * 8) * KTOT + q * CIN, &Aw[wv][c * 1024]);
  };
  stageA(0);

  // ---- fragment geometry ----
  const int lr = ln & 15, kg = ln >> 4;
  const int kgs0 = kg << 4;
  int rdA[2][2];
#pragma unroll
  for (int kc = 0; kc < 2; ++kc)
#pragma unroll
    for (int i = 0; i < 2; ++i)
      rdA[kc][i] = (((i << 4) + lr) << 7) + (((kg ^ (lr & 7)) << 4) ^ (kc << 6));

  int slotj[7];
#pragma unroll
  for (int j = 0; j < 7; ++j) {
    const int px = wn * 112 + j * 16 + lr;
    const int ph = px / 56;
    slotj[j] = (1 + ph) * 58 + (px - ph * 56) + 1;
  }

  i32x4 acc[2][7];
#pragma unroll
  for (int i = 0; i < 2; ++i)
#pragma unroll
    for (int j = 0; j < 7; ++j) acc[i][j] = (i32x4){0, 0, 0, 0};

  __syncthreads();   // halo + tap-0 A complete; ONLY block barrier

  constexpr int DC[9] = {-59, -58, -57, -1, 0, 1, 57, 58, 59};

#pragma unroll
  for (int q = 0; q < 9; ++q) {
    // own 4 gl_lds for tap q complete (tap 0 covered by syncthreads)
    if (q > 0) {
      asm volatile("s_waitcnt vmcnt(0)" ::: "memory");
      __builtin_amdgcn_sched_barrier(0);
    }
    // A fragments -> registers
    i32x4 af[2][2];
#pragma unroll
    for (int kc = 0; kc < 2; ++kc)
#pragma unroll
      for (int i = 0; i < 2; ++i)
        af[kc][i] = *(const i32x4*)&Aw[wv][rdA[kc][i]];
    // ds_reads retired before in-place restage
    asm volatile("s_waitcnt lgkmcnt(0)" ::: "memory");
    __builtin_amdgcn_sched_barrier(0);
    if (q < 8) stageA(q + 1);

    int ba[7];
#pragma unroll
    for (int j = 0; j < 7; ++j) {
      const int s_t = slotj[j] + DC[q];
      ba[j] = (s_t << 7) + (kgs0 ^ ((s_t & 7) << 4));
    }
    __builtin_amdgcn_s_setprio(1);
#pragma unroll
    for (int kc = 0; kc < 2; ++kc) {
#pragma unroll
      for (int j = 0; j < 7; ++j) {
        const i32x4 bf = *(const i32x4*)&halo[ba[j] ^ (kc << 6)];
        acc[0][j] = __builtin_amdgcn_mfma_i32_16x16x64_i8(af[kc][0], bf, acc[0][j], 0, 0, 0);
        acc[1][j] = __builtin_amdgcn_mfma_i32_16x16x64_i8(af[kc][1], bf, acc[1][j], 0, 0, 0);
      }
    }
    __builtin_amdgcn_s_setprio(0);
  }

  // ---- epilogue ----
  const int mrow = mt * 128 + wm * 32 + kg * 4;
  float* obase = out + (size_t)n * COUT * SP + sp0 + wn * 112 + lr;
#pragma unroll
  for (int i = 0; i < 2; ++i) {
#pragma unroll
    for (int r = 0; r < 4; ++r) {
      const int m = mrow + i * 16 + r;
      const float bv = bias[m];
      const float sb = bv > 0.f ? 1.f : (bv < 0.f ? -1.f : 0.f);
      float* op = obase + (size_t)m * SP;
#pragma unroll
      for (int j = 0; j < 7; ++j)
        op[j * 16] = (float)acc[i][j][r] + sb;
    }
  }
}

// ---- fallback: direct conv ----
__global__ void conv_naive(const float* __restrict__ x, const float* __restrict__ w,
                           const float* __restrict__ bias, float* __restrict__ out) {
  int idx = blockIdx.x * 256 + threadIdx.x;
  const int total = NIMG * COUT * SP;
  if (idx >= total) return;
  int sp = idx % SP;
  int o  = (idx / SP) % COUT;
  int nn = idx / (SP * COUT);
  int h = sp / HW, wx = sp - (sp / HW) * HW;
  float acc = 0.f;
  for (int c = 0; c < CIN; ++c) {
    const float* xp = x + (size_t)(nn * CIN + c) * SP;
    const float* wp = w + (size_t)(o * CIN + c) * 9;
    for (int kh = 0; kh < 3; ++kh) {
      int hhh = h + kh - 1;
      if ((unsigned)hhh >= HW) continue;
      for (int kw = 0; kw < 3; ++kw) {
        int www = wx + kw - 1;
        if ((unsigned)www >= HW) continue;
        float xv = xp[hhh * HW + www];
        float wv = wp[kh * 3 + kw];
        float xs = xv > 0.f ? 1.f : (xv < 0.f ? -1.f : 0.f);
        float wsn = wv > 0.f ? 1.f : (wv < 0.f ? -1.f : 0.f);
        acc += xs * wsn;
      }
    }
  }
  float bv = bias[o];
  out[idx] = acc + (bv > 0.f ? 1.f : (bv < 0.f ? -1.f : 0.f));
}

extern "C" void kernel_launch(void* const* d_in, const int* in_sizes, int n_in,
                              void* d_out, int out_size, void* d_ws, size_t ws_size,
                              hipStream_t stream) {
  const float* x    = (const float*)d_in[0];
  const float* w    = (const float*)d_in[1];
  const float* bias = (const float*)d_in[2];
  float* out = (float*)d_out;

  const size_t need = (size_t)1048576 + (size_t)NPIX * CIN;  // ~13.9 MB
  if (ws_size >= need) {
    u8* zerob = (u8*)d_ws;                        // 256 B zeros
    u8* wT8   = (u8*)((char*)d_ws + 512);         // 256x1152 i8
    u8* xt8   = (u8*)((char*)d_ws + 1048576);     // NHWC i8
    prep<<<1152 + 3136, 256, 0, stream>>>(x, w, wT8, xt8, zerob);
    conv_mfma<<<896, 512, 0, stream>>>(wT8, xt8, bias, zerob, out);
  } else {
    const int total = NIMG * COUT * SP;
    conv_naive<<<(total + 255) / 256, 256, 0, stream>>>(x, w, bias, out);
  }
}